// Round 1
// baseline (95.741 us; speedup 1.0000x reference)
//
#include <hip/hip_runtime.h>

// Blockwise 128-point Walsh-Hadamard transform, normalized by 1/sqrt(128).
// y[b,s,g,:] = H @ x[b,s,g,:]  (H symmetric Sylvester Hadamard / sqrt(128))
//
// Layout: each lane holds one float4; a 128-elem block spans 32 lanes.
// FWHT strides 1,2 in-register; strides 4,8,16,32,64 via ds_swizzle xor
// masks 1,2,4,8,16 (all within a 32-lane swizzle group).

typedef float f4 __attribute__((ext_vector_type(4)));

#define SWZ(x, imm) __int_as_float(__builtin_amdgcn_ds_swizzle(__float_as_int(x), (imm)))

// One cross-lane butterfly stage: partner = swizzle(val), val = s*val + partner
// (s = +1 on the low side of the pair, -1 on the high side).
#define XSTAGE(imm, s)                              \
    do {                                            \
        float p0 = SWZ(b0, imm);                    \
        float p1 = SWZ(b1, imm);                    \
        float p2 = SWZ(b2, imm);                    \
        float p3 = SWZ(b3, imm);                    \
        b0 = fmaf((s), b0, p0);                     \
        b1 = fmaf((s), b1, p1);                     \
        b2 = fmaf((s), b2, p2);                     \
        b3 = fmaf((s), b3, p3);                     \
    } while (0)

__global__ __launch_bounds__(256) void fwht128_kernel(const float* __restrict__ xp,
                                                      float* __restrict__ yp,
                                                      int n4) {
    const int lane = threadIdx.x & 63;
    // Signs for the cross-lane stages (lane bit set -> high side -> partner - mine)
    const float s4  = (lane & 1)  ? -1.0f : 1.0f;  // stride 4   <-> lane xor 1
    const float s8  = (lane & 2)  ? -1.0f : 1.0f;  // stride 8   <-> lane xor 2
    const float s16 = (lane & 4)  ? -1.0f : 1.0f;  // stride 16  <-> lane xor 4
    const float s32 = (lane & 8)  ? -1.0f : 1.0f;  // stride 32  <-> lane xor 8
    const float s64 = (lane & 16) ? -1.0f : 1.0f;  // stride 64  <-> lane xor 16
    const float scale = 0.08838834764831845f;      // 1/sqrt(128)

    const f4* __restrict__ x = (const f4*)xp;
    f4* __restrict__ y = (f4*)yp;

    int i = blockIdx.x * blockDim.x + threadIdx.x;
    const int stride = gridDim.x * blockDim.x;
    for (; i < n4; i += stride) {
        f4 v = __builtin_nontemporal_load(&x[i]);

        // stride 1 (in-register, within the float4)
        float a0 = v.x + v.y, a1 = v.x - v.y;
        float a2 = v.z + v.w, a3 = v.z - v.w;
        // stride 2 (in-register)
        float b0 = a0 + a2, b1 = a1 + a3;
        float b2 = a0 - a2, b3 = a1 - a3;

        // cross-lane stages (xor masks 1,2,4,8,16 within 32-lane group)
        XSTAGE(0x041F, s4);   // stride 4
        XSTAGE(0x081F, s8);   // stride 8
        XSTAGE(0x101F, s16);  // stride 16
        XSTAGE(0x201F, s32);  // stride 32
        XSTAGE(0x401F, s64);  // stride 64

        v.x = b0 * scale;
        v.y = b1 * scale;
        v.z = b2 * scale;
        v.w = b3 * scale;
        __builtin_nontemporal_store(v, &y[i]);
    }
}

extern "C" void kernel_launch(void* const* d_in, const int* in_sizes, int n_in,
                              void* d_out, int out_size, void* d_ws, size_t ws_size,
                              hipStream_t stream) {
    const float* x = (const float*)d_in[0];
    // d_in[1] is H — unused: the Sylvester-Hadamard structure is hardcoded as FWHT.
    float* y = (float*)d_out;

    const int n  = in_sizes[0];      // 4*4096*4096 = 67,108,864 (divisible by 1024)
    const int n4 = n / 4;            // float4 count

    const int threads = 256;
    const int blocks  = 2048;        // grid-stride; ~8 blocks/CU on 256 CUs
    fwht128_kernel<<<blocks, threads, 0, stream>>>(x, y, n4);
}